// Round 13
// baseline (122.887 us; speedup 1.0000x reference)
//
#include <hip/hip_runtime.h>
#include <math.h>

#define BB 512
#define CC 256
#define WW 64
#define NN 4096
#define EPSF 1e-16f
#define TB 512
#define LOG2E 1.44269504088896f
#define WSKIP 5e-5f   /* per-row skip: ~3.4% of batches keep tails; err ~1e-3 << 0.02 */

typedef float f32x4 __attribute__((ext_vector_type(4)));

__device__ __forceinline__ f32x4 ntload4(const float* p) {
    return __builtin_nontemporal_load((const f32x4*)p);
}

__device__ __forceinline__ float softplusf(float x) {
    return (x > 30.f) ? x : log1pf(expf(x));
}

// lgkm-only barrier: syncs LDS across the block WITHOUT draining outstanding
// global loads (plain __syncthreads emits s_waitcnt vmcnt(0) before s_barrier,
// killing cross-phase prefetch). All intra-block communication in this kernel
// is via LDS, so lgkmcnt(0) + s_barrier is sufficient.
#define BARRIER() do {                                          \
        asm volatile("s_waitcnt lgkmcnt(0)" ::: "memory");      \
        __builtin_amdgcn_s_barrier();                           \
    } while (0)

#define LOADROW(d0, d1, d2, d3, RB, ITX) do {                    \
        const float* rp_ = (RB) + (size_t)(ITX) * (128 * WW);    \
        d0 = ntload4(rp_);       d1 = ntload4(rp_ + 16);         \
        d2 = ntload4(rp_ + 32);  d3 = ntload4(rp_ + 48);         \
    } while (0)

// Uses current beta/knorm/kv0..kv3/psum/sA (reassigned per batch).
#define STEP(c0, c1, c2, c3, ITX) do {                                        \
        int n_ = qi + (ITX) * 128;                                            \
        float d_ = c0.x*kv0.x + c0.y*kv0.y + c0.z*kv0.z + c0.w*kv0.w          \
                 + c1.x*kv1.x + c1.y*kv1.y + c1.z*kv1.z + c1.w*kv1.w          \
                 + c2.x*kv2.x + c2.y*kv2.y + c2.z*kv2.z + c2.w*kv2.w          \
                 + c3.x*kv3.x + c3.y*kv3.y + c3.z*kv3.z + c3.w*kv3.w;         \
        float q_ = c0.x*c0.x + c0.y*c0.y + c0.z*c0.z + c0.w*c0.w              \
                 + c1.x*c1.x + c1.y*c1.y + c1.z*c1.z + c1.w*c1.w              \
                 + c2.x*c2.x + c2.y*c2.y + c2.z*c2.z + c2.w*c2.w              \
                 + c3.x*c3.x + c3.y*c3.y + c3.z*c3.z + c3.w*c3.w;             \
        d_ += __shfl_xor(d_, 1); q_ += __shfl_xor(q_, 1);                     \
        d_ += __shfl_xor(d_, 2); q_ += __shfl_xor(q_, 2);                     \
        if (sub == 0) {                                                       \
            float s_ = beta * d_ / (sqrtf(q_) * knorm + EPSF);                \
            float e_ = exp2f((s_ - beta) * LOG2E);                            \
            sA[n_] = e_;                                                      \
            psum += e_;                                                       \
        }                                                                     \
    } while (0)

// 256 blocks; block handles batches (bid, bid+256) pipelined: pass1(b1)'s
// first tiles are issued before weights(b0), and all mid-kernel barriers are
// lgkm-only so those loads stay in flight across the compute bubble.
__global__ __launch_bounds__(TB, 2)
void k_fused(const float* __restrict__ inputs,
             const float* __restrict__ W_fc,
             const float* __restrict__ b_fc,
             const float* __restrict__ w_pre,
             const float* __restrict__ M,
             float* __restrict__ wout,
             float* __restrict__ rout) {
    int bid = blockIdx.x;
    int b0 = bid, b1 = bid + (BB / 2);
    int t = threadIdx.x;
    int lane = t & 63;
    int wid = t >> 6;
    int sub = t & 3;
    int qi = t >> 2;   // 0..127

    __shared__ float sA[NN];
    __shared__ float in_s0[CC], in_s1[CC];
    __shared__ float k_s0[WW], k_s1[WW];
    __shared__ float raw60[6], raw61[6];
    __shared__ float par0[8], par1[8];   // 0=beta 1=g 2..4=s 5=gamma 6=knorm
    __shared__ float red[8];
    __shared__ float rred[8 * WW];

    // ---- prefetch w_pre rows for both batches ----
    const float* wpre0 = w_pre + (size_t)b0 * NN;
    const float* wpre1 = w_pre + (size_t)b1 * NN;
    float wpre_reg0[NN / TB], wpre_reg1[NN / TB];
#pragma unroll
    for (int j = 0; j < NN / TB; ++j) {
        wpre_reg0[j] = __builtin_nontemporal_load(wpre0 + t + j * TB);
        wpre_reg1[j] = __builtin_nontemporal_load(wpre1 + t + j * TB);
    }

    // ---- FC for BOTH batches in one parallel pass ----
    if (t < CC) in_s0[t] = inputs[b0 * CC + t];
    else        in_s1[t - CC] = inputs[(size_t)b1 * CC + (t - CC)];
    BARRIER();
    if (t < WW + 6) {
        float acc = b_fc[t];
        const float* wr = W_fc + t * CC;
#pragma unroll 8
        for (int c = 0; c < CC; ++c) acc = fmaf(in_s0[c], wr[c], acc);
        if (t < WW) k_s0[t] = acc; else raw60[t - WW] = acc;
    } else if (t >= CC && t < CC + WW + 6) {
        int u = t - CC;
        float acc = b_fc[u];
        const float* wr = W_fc + u * CC;
#pragma unroll 8
        for (int c = 0; c < CC; ++c) acc = fmaf(in_s1[c], wr[c], acc);
        if (u < WW) k_s1[u] = acc; else raw61[u - WW] = acc;
    }
    BARRIER();
    if (t < 64) {              // wave 0: params for b0
        float v = k_s0[t];
        float sq = v * v;
#pragma unroll
        for (int m = 1; m < 64; m <<= 1) sq += __shfl_xor(sq, m);
        if (t == 0) {
            par0[6] = sqrtf(sq);
            par0[0] = softplusf(raw60[0]);
            par0[1] = 1.f / (1.f + expf(-raw60[1]));
            float a0 = raw60[2], a1 = raw60[3], a2 = raw60[4];
            float mx3 = fmaxf(a0, fmaxf(a1, a2));
            float e0 = expf(a0 - mx3), e1 = expf(a1 - mx3), e2 = expf(a2 - mx3);
            float es = e0 + e1 + e2;
            par0[2] = e0 / es; par0[3] = e1 / es; par0[4] = e2 / es;
            par0[5] = 1.f + softplusf(raw60[5]);
        }
    } else if (t >= 256 && t < 320) {   // wave 4: params for b1
        float v = k_s1[t - 256];
        float sq = v * v;
#pragma unroll
        for (int m = 1; m < 64; m <<= 1) sq += __shfl_xor(sq, m);
        if (t == 256) {
            par1[6] = sqrtf(sq);
            par1[0] = softplusf(raw61[0]);
            par1[1] = 1.f / (1.f + expf(-raw61[1]));
            float a0 = raw61[2], a1 = raw61[3], a2 = raw61[4];
            float mx3 = fmaxf(a0, fmaxf(a1, a2));
            float e0 = expf(a0 - mx3), e1 = expf(a1 - mx3), e2 = expf(a2 - mx3);
            float es = e0 + e1 + e2;
            par1[2] = e0 / es; par1[3] = e1 / es; par1[4] = e2 / es;
            par1[5] = 1.f + softplusf(raw61[5]);
        }
    }
    BARRIER();

    const float* rb0 = M + (size_t)b0 * ((size_t)NN * WW) + (size_t)qi * WW + sub * 4;
    const float* rb1 = M + (size_t)b1 * ((size_t)NN * WW) + (size_t)qi * WW + sub * 4;
    f32x4 A0, A1, A2, A3, B0, B1, B2, B3;

    // =================== BATCH 0: pass 1 ===================
    float beta = par0[0], knorm = par0[6];
    f32x4 kv0 = *(const f32x4*)(k_s0 + sub * 4);
    f32x4 kv1 = *(const f32x4*)(k_s0 + (sub + 4) * 4);
    f32x4 kv2 = *(const f32x4*)(k_s0 + (sub + 8) * 4);
    f32x4 kv3 = *(const f32x4*)(k_s0 + (sub + 12) * 4);
    float psum = 0.f;
    LOADROW(A0, A1, A2, A3, rb0, 0);
    LOADROW(B0, B1, B2, B3, rb0, 1);
    for (int itp = 0; itp < 16; ++itp) {
        STEP(A0, A1, A2, A3, itp * 2);
        if (itp * 2 + 2 < 32) LOADROW(A0, A1, A2, A3, rb0, itp * 2 + 2);
        STEP(B0, B1, B2, B3, itp * 2 + 1);
        if (itp * 2 + 3 < 32) LOADROW(B0, B1, B2, B3, rb0, itp * 2 + 3);
    }
#pragma unroll
    for (int m = 1; m < 64; m <<= 1) psum += __shfl_xor(psum, m);
    if (lane == 0) red[wid] = psum;

    // ---- PREFETCH batch1's first two tiles (stay in flight across weights) ----
    LOADROW(A0, A1, A2, A3, rb1, 0);
    LOADROW(B0, B1, B2, B3, rb1, 1);

    BARRIER();
    {
        float S = red[0] + red[1] + red[2] + red[3] + red[4] + red[5] + red[6] + red[7];
        float g = par0[1], s0 = par0[2], s1 = par0[3], s2 = par0[4], gamma = par0[5];
        float ga = g / S;
        float omg = 1.f - g;
#pragma unroll
        for (int j = 0; j < NN / TB; ++j) {
            int i = t + j * TB;
            sA[i] = ga * sA[i] + omg * wpre_reg0[j];
        }
        BARRIER();
        float wp[NN / TB];
        float psum2 = 0.f;
#pragma unroll
        for (int j = 0; j < NN / TB; ++j) {
            int i = t + j * TB;
            int ip = (i + 1) & (NN - 1);
            int im = (i + NN - 1) & (NN - 1);
            float wt = s0 * sA[ip] + s1 * sA[i] + s2 * sA[im];
            float v = exp2f(gamma * log2f(wt));
            wp[j] = v;
            psum2 += v;
        }
#pragma unroll
        for (int m = 1; m < 64; m <<= 1) psum2 += __shfl_xor(psum2, m);
        if (lane == 0) red[wid] = psum2;
        BARRIER();
        float S2 = red[0] + red[1] + red[2] + red[3] + red[4] + red[5] + red[6] + red[7] + EPSF;
        float inv2 = 1.f / S2;
        float* wrow = wout + (size_t)b0 * NN;
#pragma unroll
        for (int j = 0; j < NN / TB; ++j) {
            int i = t + j * TB;
            float wv = wp[j] * inv2;
            sA[i] = wv;
            __builtin_nontemporal_store(wv, wrow + i);
        }
        BARRIER();
        // pass 2 (b0) with per-row skip
        f32x4 r0 = {0.f, 0.f, 0.f, 0.f}, r1 = r0, r2 = r0, r3 = r0;
        for (int it = 31; it >= 0; --it) {
            int n = qi + it * 128;
            float wn = sA[n];
            if (wn > WSKIP) {
                const float* rp = rb0 + (size_t)it * (128 * WW);
                f32x4 a0 = *(const f32x4*)(rp);
                f32x4 a1 = *(const f32x4*)(rp + 16);
                f32x4 a2 = *(const f32x4*)(rp + 32);
                f32x4 a3 = *(const f32x4*)(rp + 48);
                r0.x = fmaf(wn, a0.x, r0.x); r0.y = fmaf(wn, a0.y, r0.y);
                r0.z = fmaf(wn, a0.z, r0.z); r0.w = fmaf(wn, a0.w, r0.w);
                r1.x = fmaf(wn, a1.x, r1.x); r1.y = fmaf(wn, a1.y, r1.y);
                r1.z = fmaf(wn, a1.z, r1.z); r1.w = fmaf(wn, a1.w, r1.w);
                r2.x = fmaf(wn, a2.x, r2.x); r2.y = fmaf(wn, a2.y, r2.y);
                r2.z = fmaf(wn, a2.z, r2.z); r2.w = fmaf(wn, a2.w, r2.w);
                r3.x = fmaf(wn, a3.x, r3.x); r3.y = fmaf(wn, a3.y, r3.y);
                r3.z = fmaf(wn, a3.z, r3.z); r3.w = fmaf(wn, a3.w, r3.w);
            }
        }
#pragma unroll
        for (int m = 4; m <= 32; m <<= 1) {
            r0.x += __shfl_xor(r0.x, m); r0.y += __shfl_xor(r0.y, m);
            r0.z += __shfl_xor(r0.z, m); r0.w += __shfl_xor(r0.w, m);
            r1.x += __shfl_xor(r1.x, m); r1.y += __shfl_xor(r1.y, m);
            r1.z += __shfl_xor(r1.z, m); r1.w += __shfl_xor(r1.w, m);
            r2.x += __shfl_xor(r2.x, m); r2.y += __shfl_xor(r2.y, m);
            r2.z += __shfl_xor(r2.z, m); r2.w += __shfl_xor(r2.w, m);
            r3.x += __shfl_xor(r3.x, m); r3.y += __shfl_xor(r3.y, m);
            r3.z += __shfl_xor(r3.z, m); r3.w += __shfl_xor(r3.w, m);
        }
        if (lane < 4) {
            float* dst = rred + wid * WW + sub * 4;
            *(f32x4*)(dst)      = r0;
            *(f32x4*)(dst + 16) = r1;
            *(f32x4*)(dst + 32) = r2;
            *(f32x4*)(dst + 48) = r3;
        }
        BARRIER();
        if (t < WW) {
            float s = rred[t];
#pragma unroll
            for (int wv = 1; wv < 8; ++wv) s += rred[wv * WW + t];
            rout[(size_t)b0 * WW + t] = s;
        }
        BARRIER();
    }

    // =================== BATCH 1: pass 1 (tiles 0,1 already in flight) =======
    beta = par1[0]; knorm = par1[6];
    kv0 = *(const f32x4*)(k_s1 + sub * 4);
    kv1 = *(const f32x4*)(k_s1 + (sub + 4) * 4);
    kv2 = *(const f32x4*)(k_s1 + (sub + 8) * 4);
    kv3 = *(const f32x4*)(k_s1 + (sub + 12) * 4);
    psum = 0.f;
    for (int itp = 0; itp < 16; ++itp) {
        STEP(A0, A1, A2, A3, itp * 2);
        if (itp * 2 + 2 < 32) LOADROW(A0, A1, A2, A3, rb1, itp * 2 + 2);
        STEP(B0, B1, B2, B3, itp * 2 + 1);
        if (itp * 2 + 3 < 32) LOADROW(B0, B1, B2, B3, rb1, itp * 2 + 3);
    }
#pragma unroll
    for (int m = 1; m < 64; m <<= 1) psum += __shfl_xor(psum, m);
    if (lane == 0) red[wid] = psum;
    BARRIER();
    {
        float S = red[0] + red[1] + red[2] + red[3] + red[4] + red[5] + red[6] + red[7];
        float g = par1[1], s0 = par1[2], s1 = par1[3], s2 = par1[4], gamma = par1[5];
        float ga = g / S;
        float omg = 1.f - g;
#pragma unroll
        for (int j = 0; j < NN / TB; ++j) {
            int i = t + j * TB;
            sA[i] = ga * sA[i] + omg * wpre_reg1[j];
        }
        BARRIER();
        float wp[NN / TB];
        float psum2 = 0.f;
#pragma unroll
        for (int j = 0; j < NN / TB; ++j) {
            int i = t + j * TB;
            int ip = (i + 1) & (NN - 1);
            int im = (i + NN - 1) & (NN - 1);
            float wt = s0 * sA[ip] + s1 * sA[i] + s2 * sA[im];
            float v = exp2f(gamma * log2f(wt));
            wp[j] = v;
            psum2 += v;
        }
#pragma unroll
        for (int m = 1; m < 64; m <<= 1) psum2 += __shfl_xor(psum2, m);
        if (lane == 0) red[wid] = psum2;
        BARRIER();
        float S2 = red[0] + red[1] + red[2] + red[3] + red[4] + red[5] + red[6] + red[7] + EPSF;
        float inv2 = 1.f / S2;
        float* wrow = wout + (size_t)b1 * NN;
#pragma unroll
        for (int j = 0; j < NN / TB; ++j) {
            int i = t + j * TB;
            float wv = wp[j] * inv2;
            sA[i] = wv;
            __builtin_nontemporal_store(wv, wrow + i);
        }
        BARRIER();
        f32x4 r0 = {0.f, 0.f, 0.f, 0.f}, r1 = r0, r2 = r0, r3 = r0;
        for (int it = 31; it >= 0; --it) {
            int n = qi + it * 128;
            float wn = sA[n];
            if (wn > WSKIP) {
                const float* rp = rb1 + (size_t)it * (128 * WW);
                f32x4 a0 = *(const f32x4*)(rp);
                f32x4 a1 = *(const f32x4*)(rp + 16);
                f32x4 a2 = *(const f32x4*)(rp + 32);
                f32x4 a3 = *(const f32x4*)(rp + 48);
                r0.x = fmaf(wn, a0.x, r0.x); r0.y = fmaf(wn, a0.y, r0.y);
                r0.z = fmaf(wn, a0.z, r0.z); r0.w = fmaf(wn, a0.w, r0.w);
                r1.x = fmaf(wn, a1.x, r1.x); r1.y = fmaf(wn, a1.y, r1.y);
                r1.z = fmaf(wn, a1.z, r1.z); r1.w = fmaf(wn, a1.w, r1.w);
                r2.x = fmaf(wn, a2.x, r2.x); r2.y = fmaf(wn, a2.y, r2.y);
                r2.z = fmaf(wn, a2.z, r2.z); r2.w = fmaf(wn, a2.w, r2.w);
                r3.x = fmaf(wn, a3.x, r3.x); r3.y = fmaf(wn, a3.y, r3.y);
                r3.z = fmaf(wn, a3.z, r3.z); r3.w = fmaf(wn, a3.w, r3.w);
            }
        }
#pragma unroll
        for (int m = 4; m <= 32; m <<= 1) {
            r0.x += __shfl_xor(r0.x, m); r0.y += __shfl_xor(r0.y, m);
            r0.z += __shfl_xor(r0.z, m); r0.w += __shfl_xor(r0.w, m);
            r1.x += __shfl_xor(r1.x, m); r1.y += __shfl_xor(r1.y, m);
            r1.z += __shfl_xor(r1.z, m); r1.w += __shfl_xor(r1.w, m);
            r2.x += __shfl_xor(r2.x, m); r2.y += __shfl_xor(r2.y, m);
            r2.z += __shfl_xor(r2.z, m); r2.w += __shfl_xor(r2.w, m);
            r3.x += __shfl_xor(r3.x, m); r3.y += __shfl_xor(r3.y, m);
            r3.z += __shfl_xor(r3.z, m); r3.w += __shfl_xor(r3.w, m);
        }
        if (lane < 4) {
            float* dst = rred + wid * WW + sub * 4;
            *(f32x4*)(dst)      = r0;
            *(f32x4*)(dst + 16) = r1;
            *(f32x4*)(dst + 32) = r2;
            *(f32x4*)(dst + 48) = r3;
        }
        BARRIER();
        if (t < WW) {
            float s = rred[t];
#pragma unroll
            for (int wv = 1; wv < 8; ++wv) s += rred[wv * WW + t];
            rout[(size_t)b1 * WW + t] = s;
        }
    }
}

extern "C" void kernel_launch(void* const* d_in, const int* in_sizes, int n_in,
                              void* d_out, int out_size, void* d_ws, size_t ws_size,
                              hipStream_t stream) {
    const float* inputs = (const float*)d_in[0];
    const float* w_pre  = (const float*)d_in[1];
    const float* M      = (const float*)d_in[2];
    const float* W_fc   = (const float*)d_in[3];
    const float* b_fc   = (const float*)d_in[4];

    float* out = (float*)d_out;
    float* r_out = out;                 // B*W floats
    float* w_out = out + BB * WW;       // B*N floats

    k_fused<<<BB / 2, TB, 0, stream>>>(inputs, W_fc, b_fc, w_pre, M, w_out, r_out);
}